// Round 4
// baseline (147.429 us; speedup 1.0000x reference)
//
#include <hip/hip_runtime.h>

typedef _Float16 f16;
typedef f16 h8 __attribute__((ext_vector_type(8)));
typedef float f32x4 __attribute__((ext_vector_type(4)));
typedef unsigned int uint;

#define BM 32
#define WG_SIZE 512
#define KS_E 283         // ceil(9040/32); K' = 10*904 padded color-blocks
#define CSTR 920         // color row stride bytes (8-aligned, bank-clean: 230%32=6)

// LDS strides (halves / floats)
#define SH 136
#define SAZ 232          // [y(128) z(64) gf(16) zeropad(16)] + 8
#define SLOG 68

// ws layout (halves)
#define N_W1P (8*KS_E*512)   // 1,159,168  encoder B fragments
#define OW2   0
#define OWY   16384
#define OWZ   32768
#define ORZ1  40960
#define ORZ2  55296
#define ORY1  59392
#define ORY2  73728
#define OS1   81920
#define OS2   90112
#define N_SMH 94208

__device__ __forceinline__ float geluf(float x){
  return 0.5f * x * (1.0f + erff(x * 0.70710678118654752f));
}

#define MFMA16(a,b,c) __builtin_amdgcn_mfma_f32_16x16x32_f16(a, b, c, 0, 0, 0)

// one 16x16 C tile over K = nks*32; A from LDS (k = (lane>>4)*8+e), B prep-packed (same k-map)
__device__ __forceinline__ f32x4 mfma_tile(const f16* __restrict__ act, int strideH,
                                           const f16* __restrict__ Wbase,
                                           int nks, f32x4 acc, int lane){
  #pragma unroll
  for (int ks = 0; ks < nks; ++ks){
    h8 a = *(const h8*)(act + (lane&15)*strideH + ks*32 + (lane>>4)*8);
    h8 b = *(const h8*)(Wbase + ks*512 + lane*8);
    acc = MFMA16(a, b, acc);
  }
  return acc;
}

__device__ __forceinline__ f32x4 cinit(const float* __restrict__ bias, int Nb, int lane){
  float v = bias[Nb + (lane&15)];
  f32x4 c; c[0]=v; c[1]=v; c[2]=v; c[3]=v;
  return c;
}

// C layout (HW-verified): col = lane&15, row = (lane>>4)*4 + reg
__device__ __forceinline__ void storeC16(f16* __restrict__ dst, int stride, int ro, int Nb,
                                         f32x4 c, int lane, bool dogelu){
  int col = Nb + (lane&15);
  int r0  = ro + (lane>>4)*4;
  #pragma unroll
  for (int r = 0; r < 4; ++r){
    float v = c[r];
    if (dogelu) v = geluf(v);
    dst[(r0+r)*stride + col] = (f16)v;
  }
}

// ---------------- prep ----------------
// seg 1: w1 (coalesced read) -> encoder B fragments, k = 904*c + p
// seg 2: zero-fill pad slots (p in [900,904) and k in [9040,9056))
// seg 3: small weights -> MFMA fragment order (as before)
__global__ void prep_kernel(const float* __restrict__ w1,
  const float* __restrict__ w2, const float* __restrict__ wy, const float* __restrict__ wz,
  const float* __restrict__ rz1, const float* __restrict__ rz2,
  const float* __restrict__ ry1, const float* __restrict__ ry2,
  const float* __restrict__ sel1, const float* __restrict__ sel2, f16* __restrict__ ws)
{
  int idx = blockIdx.x * 256 + threadIdx.x;
  if (idx < 9000*128){
    int row = idx >> 7;          // 0..8999 = p*10+c
    int n   = idx & 127;
    int p   = row / 10;
    int c   = row - p*10;
    int k   = 904*c + p;
    int nt  = n >> 4;
    int ks  = k >> 5;
    int lane = (((k>>3)&3)<<4) | (n&15);
    int e   = k & 7;
    ws[((nt*KS_E + ks)<<9) + (lane<<3) + e] = (f16)w1[idx];
    return;
  }
  int i2 = idx - 9000*128;
  if (i2 < 7168){
    int k, n;
    if (i2 < 5120){
      int c = i2 >> 9, rest = i2 & 511;
      k = 904*c + 900 + (rest >> 7);
      n = rest & 127;
    } else {
      int j = i2 - 5120;
      k = 9040 + (j >> 7);
      n = j & 127;
    }
    int nt = n >> 4, ks = k >> 5;
    int lane = (((k>>3)&3)<<4) | (n&15);
    ws[((nt*KS_E + ks)<<9) + (lane<<3) + (k&7)] = (f16)0.f;
    return;
  }
  int r = i2 - 7168;
  if (r >= N_SMH) return;
  const float* src; int Ksrc, N, KS, off, perm = 0;
  if      (r < OWY) { src=w2;   Ksrc=128; N=128; KS=4; off=OW2; }
  else if (r < OWZ) { src=wy;   Ksrc=128; N=128; KS=4; off=OWY; }
  else if (r < ORZ1){ src=wz;   Ksrc=128; N=64;  KS=4; off=OWZ; }
  else if (r < ORZ2){ src=rz1;  Ksrc=208; N=64;  KS=7; off=ORZ1; }
  else if (r < ORY1){ src=rz2;  Ksrc=64;  N=64;  KS=2; off=ORZ2; }
  else if (r < ORY2){ src=ry1;  Ksrc=208; N=64;  KS=7; off=ORY1; perm=1; }
  else if (r < OS1) { src=ry2;  Ksrc=64;  N=128; KS=2; off=ORY2; }
  else if (r < OS2) { src=sel1; Ksrc=128; N=64;  KS=4; off=OS1; }
  else              { src=sel2; Ksrc=64;  N=64;  KS=2; off=OS2; }
  int l    = r - off;
  int e    = l & 7;
  int lane = (l >> 3) & 63;
  int frag = l >> 9;
  int kst  = frag % KS;
  int nt   = frag / KS;
  int k    = kst*32 + (lane>>4)*8 + e;
  int o    = nt*16 + (lane&15);
  float v = 0.f;
  if (perm){
    int sr = (k < 128) ? 64 + k : (k < 192) ? k - 128 : (k < 208) ? k : -1;
    if (sr >= 0) v = src[sr*N + o];
  } else if (k < Ksrc) v = src[k*N + o];
  ws[N_W1P + r] = (f16)v;
}

// ---------------- fused main kernel ----------------
extern "C" __global__ __launch_bounds__(WG_SIZE, 2) void fused_kernel(
  const int* __restrict__ grd, const float* __restrict__ gfeat, const float* __restrict__ gum,
  const float* __restrict__ b1, const float* __restrict__ b2,
  const float* __restrict__ by, const float* __restrict__ bz,
  const float* __restrict__ rzb1, const float* __restrict__ rzb2,
  const float* __restrict__ ryb1, const float* __restrict__ ryb2,
  const float* __restrict__ sb1, const float* __restrict__ sb2,
  const f16* __restrict__ ws, float* __restrict__ out)
{
  __shared__ __align__(16) char colL[32*CSTR];
  __shared__ __align__(16) f16 Hb[32*SH];
  __shared__ __align__(16) f16 Bb[32*SH];
  __shared__ __align__(16) f16 Az[32*SAZ];
  __shared__ __align__(16) float Lb[32*SLOG];

  const int t  = threadIdx.x;
  const int s0 = blockIdx.x * BM;
  const int lane  = t & 63;
  const int w     = t >> 6;        // 0..7
  const int st    = w & 1;         // sample-half
  const int ns    = w >> 1;        // N-slice 0..3
  const int slane = t >> 4;        // 0..31 (prologue/softmax roles)
  const int flane = t & 15;

  // ---- prologue: pack colors to u8 rows + stage grid features / zero K-pad ----
  {
    const uint4* gv = (const uint4*)(grd + (size_t)s0 * 900);
    #pragma unroll
    for (int it = 0; it < 15; ++it){
      int idx4 = it*512 + t;
      if (idx4 < 7200){
        uint4 v = gv[idx4];
        uint pk = (v.x & 255u) | ((v.y & 255u) << 8) | ((v.z & 255u) << 16) | ((v.w & 255u) << 24);
        uint s  = (uint)(idx4 * 9321u) >> 21;   // idx4 / 225
        uint p4 = (uint)idx4 - s * 225u;
        *(uint*)(colL + s*CSTR + p4*4) = pk;
      }
    }
    Az[slane*SAZ + 192 + flane] = (f16)gfeat[(size_t)(s0 + slane)*16 + flane];
    Az[slane*SAZ + 208 + flane] = (f16)0.f;
  }
  __syncthreads();

  // ---- phase E: h = gelu(onehot(grid) @ w1 + b1) as MFMA, A built in-register ----
  {
    const int nt0 = ns * 2;
    const uint r8 = (uint)((lane >> 4) * 8);
    const char* colRow = colL + (st*16 + (lane & 15)) * CSTR;
    const f16* W0 = ws + (size_t)(nt0    * KS_E) * 512 + lane*8;
    const f16* W1 = ws + (size_t)((nt0+1)* KS_E) * 512 + lane*8;

    f32x4 acc0 = cinit(b1, nt0*16,      lane);
    f32x4 acc1 = cinit(b1, nt0*16 + 16, lane);

    auto abuild = [&](uint k0v) -> h8 {
      uint q  = k0v >> 3;
      uint c  = (q * 2320u) >> 18;        // exact /113 for q<16384
      uint p0 = (q - 113u * c) << 3;      // byte offset, 8-aligned
      uint2 wv = *(const uint2*)(colRow + p0);
      uint cc4 = c * 0x01010101u;
      uint x0 = wv.x ^ cc4, x1 = wv.y ^ cc4;
      // exact per-byte zero detect -> 0x01 at matches
      uint m0 = (~(x0 | ((x0 | 0x80808080u) - 0x01010101u)) & 0x80808080u) >> 7;
      uint m1 = (~(x1 | ((x1 | 0x80808080u) - 0x01010101u)) & 0x80808080u) >> 7;
      m0 *= 0x3Cu; m1 *= 0x3Cu;           // 0x3C at matches
      union { uint u[4]; h8 v; } af;
      af.u[0] = __builtin_amdgcn_perm(0u, m0, 0x01050004u);  // [0,b0,0,b1] -> halves 0x3C00
      af.u[1] = __builtin_amdgcn_perm(0u, m0, 0x03050204u);
      af.u[2] = __builtin_amdgcn_perm(0u, m1, 0x01050004u);
      af.u[3] = __builtin_amdgcn_perm(0u, m1, 0x03050204u);
      return af.v;
    };

    h8 bc0 = *(const h8*)(W0);
    h8 bc1 = *(const h8*)(W1);
    h8 bn0 = *(const h8*)(W0 + 512);
    h8 bn1 = *(const h8*)(W1 + 512);
    uint k0 = r8;
    #pragma unroll 4
    for (int ks = 0; ks < KS_E - 2; ++ks){
      h8 bf0 = *(const h8*)(W0 + (size_t)(ks+2)*512);
      h8 bf1 = *(const h8*)(W1 + (size_t)(ks+2)*512);
      h8 a = abuild(k0);
      acc0 = MFMA16(a, bc0, acc0);
      acc1 = MFMA16(a, bc1, acc1);
      bc0 = bn0; bc1 = bn1; bn0 = bf0; bn1 = bf1;
      k0 += 32;
    }
    { // ks = 281, 282
      h8 a = abuild(k0);
      acc0 = MFMA16(a, bc0, acc0);
      acc1 = MFMA16(a, bc1, acc1);
      k0 += 32;
      a = abuild(k0);
      acc0 = MFMA16(a, bn0, acc0);
      acc1 = MFMA16(a, bn1, acc1);
    }
    storeC16(Hb, SH, st*16, nt0*16,      acc0, lane, true);
    storeC16(Hb, SH, st*16, nt0*16 + 16, acc1, lane, true);
  }
  __syncthreads();

  // ---- phases 2-4: MFMA, wave (st, ns) ----
  const f16* SMW = ws + N_W1P;
  const f16* actH = Hb + st*16*SH;
  const f16* actB = Bb + st*16*SH;
  const f16* actA = Az + st*16*SAZ;

  // enc L2: h2 = gelu(h @ w2 + b2)
  {
    f32x4 c0 = cinit(b2, ns*32,      lane);
    f32x4 c1 = cinit(b2, ns*32 + 16, lane);
    c0 = mfma_tile(actH, SH, SMW + OW2 + (ns*2+0)*4*512, 4, c0, lane);
    c1 = mfma_tile(actH, SH, SMW + OW2 + (ns*2+1)*4*512, 4, c1, lane);
    storeC16(Bb, SH, st*16, ns*32,      c0, lane, true);
    storeC16(Bb, SH, st*16, ns*32 + 16, c1, lane, true);
  }
  __syncthreads();

  // heads: y = h2@wy+by ; z = h2@wz+bz
  {
    f32x4 y0 = cinit(by, ns*32,      lane);
    f32x4 y1 = cinit(by, ns*32 + 16, lane);
    f32x4 z0 = cinit(bz, ns*16,      lane);
    y0 = mfma_tile(actB, SH, SMW + OWY + (ns*2+0)*4*512, 4, y0, lane);
    y1 = mfma_tile(actB, SH, SMW + OWY + (ns*2+1)*4*512, 4, y1, lane);
    z0 = mfma_tile(actB, SH, SMW + OWZ + ns*4*512,       4, z0, lane);
    storeC16(Az, SAZ, st*16, ns*32,       y0, lane, false);
    storeC16(Az, SAZ, st*16, ns*32 + 16,  y1, lane, false);
    storeC16(Az, SAZ, st*16, 128 + ns*16, z0, lane, false);
  }
  __syncthreads();

  // 3 refinement cycles
  #pragma unroll 1
  for (int cyc = 0; cyc < 3; ++cyc){
    { // hid = gelu([y,z,gf] @ rz1 + rzb1)   K=224
      f32x4 h0 = cinit(rzb1, ns*16, lane);
      h0 = mfma_tile(actA, SAZ, SMW + ORZ1 + ns*7*512, 7, h0, lane);
      storeC16(Bb, SH, st*16, ns*16, h0, lane, true);
    }
    __syncthreads();
    { // z = hid @ rz2 + rzb2   K=64
      f32x4 z = cinit(rzb2, ns*16, lane);
      z = mfma_tile(actB, SH, SMW + ORZ2 + ns*2*512, 2, z, lane);
      storeC16(Az, SAZ, st*16, 128 + ns*16, z, lane, false);
    }
    __syncthreads();
    { // hid = gelu([z,y,gf] @ ry1 + ryb1)   K=224 (perm-packed)
      f32x4 h1 = cinit(ryb1, ns*16, lane);
      h1 = mfma_tile(actA, SAZ, SMW + ORY1 + ns*7*512, 7, h1, lane);
      storeC16(Bb, SH, st*16, ns*16, h1, lane, true);
    }
    __syncthreads();
    { // y = hid @ ry2 + ryb2   K=64, N=128
      f32x4 y0 = cinit(ryb2, ns*32,      lane);
      f32x4 y1 = cinit(ryb2, ns*32 + 16, lane);
      y0 = mfma_tile(actB, SH, SMW + ORY2 + (ns*2+0)*2*512, 2, y0, lane);
      y1 = mfma_tile(actB, SH, SMW + ORY2 + (ns*2+1)*2*512, 2, y1, lane);
      storeC16(Az, SAZ, st*16, ns*32,      y0, lane, false);
      storeC16(Az, SAZ, st*16, ns*32 + 16, y1, lane, false);
    }
    __syncthreads();
  }

  // selector
  {
    f32x4 s1 = cinit(sb1, ns*16, lane);
    s1 = mfma_tile(actA, SAZ, SMW + OS1 + ns*4*512, 4, s1, lane);
    storeC16(Bb, SH, st*16, ns*16, s1, lane, true);
  }
  __syncthreads();
  {
    f32x4 lg = cinit(sb2, ns*16, lane);
    lg = mfma_tile(actB, SH, SMW + OS2 + ns*2*512, 2, lg, lane);
    int col = ns*16 + (lane & 15);
    int r0  = st*16 + (lane >> 4) * 4;
    #pragma unroll
    for (int rr = 0; rr < 4; ++rr)
      Lb[(r0+rr)*SLOG + col] = lg[rr] + gum[(size_t)(s0 + r0 + rr)*64 + col];
  }
  __syncthreads();

  // softmax (16 threads/sample, redundant row reduce)
  {
    const float* row = Lb + slane*SLOG;
    float m = -3.0e38f;
    #pragma unroll
    for (int k4 = 0; k4 < 16; ++k4){
      float4 v = *(const float4*)(row + k4*4);
      m = fmaxf(m, fmaxf(fmaxf(v.x,v.y), fmaxf(v.z,v.w)));
    }
    float ssum = 0.f;
    #pragma unroll
    for (int k4 = 0; k4 < 16; ++k4){
      float4 v = *(const float4*)(row + k4*4);
      ssum += __expf(v.x-m)+__expf(v.y-m)+__expf(v.z-m)+__expf(v.w-m);
    }
    float inv = 1.0f / ssum;
    const size_t gsamp = (size_t)(s0 + slane);
    #pragma unroll
    for (int j = 0; j < 4; ++j){
      int o = flane + 16*j;
      out[gsamp*64 + o] = __expf(row[o]-m) * inv;
    }
  }
}

extern "C" void kernel_launch(void* const* d_in, const int* in_sizes, int n_in,
                              void* d_out, int out_size, void* d_ws, size_t ws_size,
                              hipStream_t stream) {
  const int*   grd   = (const int*)d_in[0];
  const float* gfeat = (const float*)d_in[1];
  const float* gum   = (const float*)d_in[2];
  const float* w1    = (const float*)d_in[3];
  const float* b1    = (const float*)d_in[4];
  const float* w2    = (const float*)d_in[5];
  const float* b2    = (const float*)d_in[6];
  const float* wy    = (const float*)d_in[7];
  const float* byb   = (const float*)d_in[8];
  const float* wz    = (const float*)d_in[9];
  const float* bz    = (const float*)d_in[10];
  const float* rz1   = (const float*)d_in[11];
  const float* rzb1  = (const float*)d_in[12];
  const float* rz2   = (const float*)d_in[13];
  const float* rzb2  = (const float*)d_in[14];
  const float* ry1   = (const float*)d_in[15];
  const float* ryb1  = (const float*)d_in[16];
  const float* ry2   = (const float*)d_in[17];
  const float* ryb2  = (const float*)d_in[18];
  const float* sel1  = (const float*)d_in[19];
  const float* sb1   = (const float*)d_in[20];
  const float* sel2  = (const float*)d_in[21];
  const float* sb2   = (const float*)d_in[22];

  f16* ws = (f16*)d_ws;
  float* outp = (float*)d_out;

  const int prep_total = 9000*128 + 7168 + N_SMH;   // 1,253,376 = 4896*256
  prep_kernel<<<prep_total/256, 256, 0, stream>>>(
      w1, w2, wy, wz, rz1, rz2, ry1, ry2, sel1, sel2, ws);

  fused_kernel<<<8192/BM, WG_SIZE, 0, stream>>>(
      grd, gfeat, gum, b1, b2, byb, bz, rzb1, rzb2, ryb1, ryb2, sb1, sb2, ws, outp);
}

// Round 5
// 75.110 us; speedup vs baseline: 1.9628x; 1.9628x over previous
//
#include <hip/hip_runtime.h>

typedef _Float16 f16;
typedef f16 h8 __attribute__((ext_vector_type(8)));
typedef float f32x4 __attribute__((ext_vector_type(4)));
typedef unsigned int uint;

#define BM 32
#define WG_SIZE 512
#define KS_E 284         // ceil(9040/32)+1 pad; K' = 10*904 padded color-blocks, +1 zero block
#define CSTR 920         // color row stride bytes

// LDS strides (halves / floats)
#define SH 136
#define SAZ 232          // [y(128) z(64) gf(16) zeropad(16)] + 8
#define SLOG 68

// ws layout (halves)
#define N_W1P (8*KS_E*512)   // encoder B fragments (1,163,264)
#define OW2   0
#define OWY   16384
#define OWZ   32768
#define ORZ1  40960
#define ORZ2  55296
#define ORY1  59392
#define ORY2  73728
#define OS1   81920
#define OS2   90112
#define N_SMH 94208
// Wr (LDS-staged refinement weights) internal offsets (halves, rel. ORZ1)
#define WR_RZ1 0
#define WR_RZ2 14336
#define WR_RY1 18432
#define WR_RY2 32768
#define WR_LEN 40960     // 80 KiB

__device__ __forceinline__ float geluf(float x){
  return 0.5f * x * (1.0f + erff(x * 0.70710678118654752f));
}

__device__ __forceinline__ void gll16(const void* g, void* l){
  __builtin_amdgcn_global_load_lds((const __attribute__((address_space(1))) void*)g,
                                   (__attribute__((address_space(3))) void*)l, 16, 0, 0);
}

#define MFMA16(a,b,c) __builtin_amdgcn_mfma_f32_16x16x32_f16(a, b, c, 0, 0, 0)

// one 16x16 C tile over K = nks*32; A from LDS (k = (lane>>4)*8+e), B prep-packed (same k-map)
__device__ __forceinline__ f32x4 mfma_tile(const f16* __restrict__ act, int strideH,
                                           const f16* __restrict__ Wbase,
                                           int nks, f32x4 acc, int lane){
  #pragma unroll
  for (int ks = 0; ks < nks; ++ks){
    h8 a = *(const h8*)(act + (lane&15)*strideH + ks*32 + (lane>>4)*8);
    h8 b = *(const h8*)(Wbase + ks*512 + lane*8);
    acc = MFMA16(a, b, acc);
  }
  return acc;
}

__device__ __forceinline__ f32x4 cinit(const float* __restrict__ bias, int Nb, int lane){
  float v = bias[Nb + (lane&15)];
  f32x4 c; c[0]=v; c[1]=v; c[2]=v; c[3]=v;
  return c;
}

// C layout (HW-verified): col = lane&15, row = (lane>>4)*4 + reg
__device__ __forceinline__ void storeC16(f16* __restrict__ dst, int stride, int ro, int Nb,
                                         f32x4 c, int lane, bool dogelu){
  int col = Nb + (lane&15);
  int r0  = ro + (lane>>4)*4;
  #pragma unroll
  for (int r = 0; r < 4; ++r){
    float v = c[r];
    if (dogelu) v = geluf(v);
    dst[(r0+r)*stride + col] = (f16)v;
  }
}

// ---------------- prep ----------------
__global__ void prep_kernel(const float* __restrict__ w1,
  const float* __restrict__ w2, const float* __restrict__ wy, const float* __restrict__ wz,
  const float* __restrict__ rz1, const float* __restrict__ rz2,
  const float* __restrict__ ry1, const float* __restrict__ ry2,
  const float* __restrict__ sel1, const float* __restrict__ sel2, f16* __restrict__ ws)
{
  int idx = blockIdx.x * 256 + threadIdx.x;
  if (idx < 9000*128){
    int row = idx >> 7;          // 0..8999 = p*10+c
    int n   = idx & 127;
    int p   = row / 10;
    int c   = row - p*10;
    int k   = 904*c + p;
    int nt  = n >> 4;
    int ks  = k >> 5;
    int lane = (((k>>3)&3)<<4) | (n&15);
    int e   = k & 7;
    ws[((nt*KS_E + ks)<<9) + (lane<<3) + e] = (f16)w1[idx];
    return;
  }
  int i2 = idx - 9000*128;
  if (i2 < 11264){               // zero-fill pad: p in [900,904) and k in [9040,9088)
    int k, n;
    if (i2 < 5120){
      int c = i2 >> 9, rest = i2 & 511;
      k = 904*c + 900 + (rest >> 7);
      n = rest & 127;
    } else {
      int j = i2 - 5120;
      k = 9040 + (j >> 7);
      n = j & 127;
    }
    int nt = n >> 4, ks = k >> 5;
    int lane = (((k>>3)&3)<<4) | (n&15);
    ws[((nt*KS_E + ks)<<9) + (lane<<3) + (k&7)] = (f16)0.f;
    return;
  }
  int r = i2 - 11264;
  if (r >= N_SMH) return;
  const float* src; int Ksrc, N, KS, off, perm = 0;
  if      (r < OWY) { src=w2;   Ksrc=128; N=128; KS=4; off=OW2; }
  else if (r < OWZ) { src=wy;   Ksrc=128; N=128; KS=4; off=OWY; }
  else if (r < ORZ1){ src=wz;   Ksrc=128; N=64;  KS=4; off=OWZ; }
  else if (r < ORZ2){ src=rz1;  Ksrc=208; N=64;  KS=7; off=ORZ1; }
  else if (r < ORY1){ src=rz2;  Ksrc=64;  N=64;  KS=2; off=ORZ2; }
  else if (r < ORY2){ src=ry1;  Ksrc=208; N=64;  KS=7; off=ORY1; perm=1; }
  else if (r < OS1) { src=ry2;  Ksrc=64;  N=128; KS=2; off=ORY2; }
  else if (r < OS2) { src=sel1; Ksrc=128; N=64;  KS=4; off=OS1; }
  else              { src=sel2; Ksrc=64;  N=64;  KS=2; off=OS2; }
  int l    = r - off;
  int e    = l & 7;
  int lane = (l >> 3) & 63;
  int frag = l >> 9;
  int kst  = frag % KS;
  int nt   = frag / KS;
  int k    = kst*32 + (lane>>4)*8 + e;
  int o    = nt*16 + (lane&15);
  float v = 0.f;
  if (perm){
    int sr = (k < 128) ? 64 + k : (k < 192) ? k - 128 : (k < 208) ? k : -1;
    if (sr >= 0) v = src[sr*N + o];
  } else if (k < Ksrc) v = src[k*N + o];
  ws[N_W1P + r] = (f16)v;
}

// ---------------- fused main kernel ----------------
extern "C" __global__ __launch_bounds__(WG_SIZE, 2) void fused_kernel(
  const int* __restrict__ grd, const float* __restrict__ gfeat, const float* __restrict__ gum,
  const float* __restrict__ b1, const float* __restrict__ b2,
  const float* __restrict__ by, const float* __restrict__ bz,
  const float* __restrict__ rzb1, const float* __restrict__ rzb2,
  const float* __restrict__ ryb1, const float* __restrict__ ryb2,
  const float* __restrict__ sb1, const float* __restrict__ sb2,
  const f16* __restrict__ ws, float* __restrict__ out)
{
  __shared__ __align__(16) char colL[32*CSTR];
  __shared__ __align__(16) f16 Wr[WR_LEN];      // refinement weights, staged once
  __shared__ __align__(16) f16 Hb[32*SH];
  __shared__ __align__(16) f16 Bb[32*SH];
  __shared__ __align__(16) f16 Az[32*SAZ];
  __shared__ __align__(16) float Lb[32*SLOG];

  const int t  = threadIdx.x;
  const int s0 = blockIdx.x * BM;
  const int lane  = t & 63;
  const int w     = t >> 6;        // 0..7
  const int st    = w & 1;         // sample-half (phases 2-4)
  const int ns    = w >> 1;        // N-slice (phases 2-4)
  const int slane = t >> 4;        // 0..31
  const int flane = t & 15;

  // ---- stage refinement weights global->LDS (consumed much later; latency free) ----
  {
    const char* src = (const char*)(ws + N_W1P + ORZ1);
    char* dst = (char*)Wr;
    #pragma unroll
    for (int i = 0; i < 10; ++i)
      gll16(src + i*8192 + t*16, dst + i*8192 + t*16);
  }

  // ---- prologue: pack colors to u8 rows + stage grid features / zero K-pad ----
  {
    const uint4* gv = (const uint4*)(grd + (size_t)s0 * 900);
    #pragma unroll
    for (int it = 0; it < 15; ++it){
      int idx4 = it*512 + t;
      if (idx4 < 7200){
        uint4 v = gv[idx4];
        uint pk = (v.x & 255u) | ((v.y & 255u) << 8) | ((v.z & 255u) << 16) | ((v.w & 255u) << 24);
        uint s  = (uint)(idx4 * 9321u) >> 21;   // idx4 / 225
        uint p4 = (uint)idx4 - s * 225u;
        *(uint*)(colL + s*CSTR + p4*4) = pk;
      }
    }
    Az[slane*SAZ + 192 + flane] = (f16)gfeat[(size_t)(s0 + slane)*16 + flane];
    Az[slane*SAZ + 208 + flane] = (f16)0.f;
  }
  __syncthreads();

  // ---- phase E: h = gelu(onehot(grid) @ w1 + b1); wave = one N-tile, both sample halves ----
  {
    const uint r8 = (uint)((lane >> 4) * 8);
    const char* colRowA = colL + (lane & 15) * CSTR;
    const char* colRowB = colL + (16 + (lane & 15)) * CSTR;
    const f16* Wp = ws + (size_t)(w * KS_E) * 512 + lane*8;

    f32x4 acc0 = cinit(b1, w*16, lane);
    f32x4 acc1 = acc0;

    auto abuild = [&](const char* colRow, uint k0v) -> h8 {
      uint q  = k0v >> 3;
      uint c  = (q * 2320u) >> 18;        // exact /113 for q<16384
      uint p0 = (q - 113u * c) << 3;      // byte offset, 8-aligned
      uint2 wv = *(const uint2*)(colRow + p0);
      uint cc4 = c * 0x01010101u;
      uint x0 = wv.x ^ cc4, x1 = wv.y ^ cc4;
      uint m0 = (~(x0 | ((x0 | 0x80808080u) - 0x01010101u)) & 0x80808080u) >> 7;
      uint m1 = (~(x1 | ((x1 | 0x80808080u) - 0x01010101u)) & 0x80808080u) >> 7;
      m0 *= 0x3Cu; m1 *= 0x3Cu;           // 0x3C at matches -> halves 0x3C00 = 1.0h
      union { uint u[4]; h8 v; } af;
      af.u[0] = __builtin_amdgcn_perm(0u, m0, 0x01050004u);
      af.u[1] = __builtin_amdgcn_perm(0u, m0, 0x03050204u);
      af.u[2] = __builtin_amdgcn_perm(0u, m1, 0x01050004u);
      af.u[3] = __builtin_amdgcn_perm(0u, m1, 0x03050204u);
      return af.v;
    };

    h8 q0 = *(const h8*)(Wp);
    h8 q1 = *(const h8*)(Wp + 512);
    h8 q2 = *(const h8*)(Wp + 1024);
    h8 q3 = *(const h8*)(Wp + 1536);
    uint k0 = r8;

#define ESTEP(Q, PFIDX) { \
      h8 a0 = abuild(colRowA, k0); \
      h8 a1 = abuild(colRowB, k0); \
      acc0 = MFMA16(a0, Q, acc0); \
      acc1 = MFMA16(a1, Q, acc1); \
      Q = *(const h8*)(Wp + (size_t)(PFIDX)*512); \
      k0 += 32; }
#define ETAIL(Q) { \
      h8 a0 = abuild(colRowA, k0); \
      h8 a1 = abuild(colRowB, k0); \
      acc0 = MFMA16(a0, Q, acc0); \
      acc1 = MFMA16(a1, Q, acc1); \
      k0 += 32; }

    #pragma unroll 2
    for (int it = 0; it < 70; ++it){
      ESTEP(q0, it*4 + 4)
      ESTEP(q1, it*4 + 5)
      ESTEP(q2, it*4 + 6)
      ESTEP(q3, it*4 + 7)
    }
    ETAIL(q0) ETAIL(q1) ETAIL(q2) ETAIL(q3)
#undef ESTEP
#undef ETAIL

    storeC16(Hb, SH, 0,  w*16, acc0, lane, true);
    storeC16(Hb, SH, 16, w*16, acc1, lane, true);
  }
  __syncthreads();

  // ---- phases 2-4: MFMA, wave (st, ns) ----
  const f16* SMW = ws + N_W1P;
  const f16* actH = Hb + st*16*SH;
  const f16* actB = Bb + st*16*SH;
  const f16* actA = Az + st*16*SAZ;

  // enc L2: h2 = gelu(h @ w2 + b2)
  {
    f32x4 c0 = cinit(b2, ns*32,      lane);
    f32x4 c1 = cinit(b2, ns*32 + 16, lane);
    c0 = mfma_tile(actH, SH, SMW + OW2 + (ns*2+0)*4*512, 4, c0, lane);
    c1 = mfma_tile(actH, SH, SMW + OW2 + (ns*2+1)*4*512, 4, c1, lane);
    storeC16(Bb, SH, st*16, ns*32,      c0, lane, true);
    storeC16(Bb, SH, st*16, ns*32 + 16, c1, lane, true);
  }
  __syncthreads();

  // heads: y = h2@wy+by ; z = h2@wz+bz
  {
    f32x4 y0 = cinit(by, ns*32,      lane);
    f32x4 y1 = cinit(by, ns*32 + 16, lane);
    f32x4 z0 = cinit(bz, ns*16,      lane);
    y0 = mfma_tile(actB, SH, SMW + OWY + (ns*2+0)*4*512, 4, y0, lane);
    y1 = mfma_tile(actB, SH, SMW + OWY + (ns*2+1)*4*512, 4, y1, lane);
    z0 = mfma_tile(actB, SH, SMW + OWZ + ns*4*512,       4, z0, lane);
    storeC16(Az, SAZ, st*16, ns*32,       y0, lane, false);
    storeC16(Az, SAZ, st*16, ns*32 + 16,  y1, lane, false);
    storeC16(Az, SAZ, st*16, 128 + ns*16, z0, lane, false);
  }
  asm volatile("s_waitcnt vmcnt(0)" ::: "memory");   // Wr staging certainly done
  __syncthreads();

  // 3 refinement cycles (weights from LDS)
  #pragma unroll 1
  for (int cyc = 0; cyc < 3; ++cyc){
    { // hid = gelu([y,z,gf] @ rz1 + rzb1)   K=224
      f32x4 h0 = cinit(rzb1, ns*16, lane);
      h0 = mfma_tile(actA, SAZ, Wr + WR_RZ1 + ns*7*512, 7, h0, lane);
      storeC16(Bb, SH, st*16, ns*16, h0, lane, true);
    }
    __syncthreads();
    { // z = hid @ rz2 + rzb2   K=64
      f32x4 z = cinit(rzb2, ns*16, lane);
      z = mfma_tile(actB, SH, Wr + WR_RZ2 + ns*2*512, 2, z, lane);
      storeC16(Az, SAZ, st*16, 128 + ns*16, z, lane, false);
    }
    __syncthreads();
    { // hid = gelu([z,y,gf] @ ry1 + ryb1)   K=224 (perm-packed)
      f32x4 h1 = cinit(ryb1, ns*16, lane);
      h1 = mfma_tile(actA, SAZ, Wr + WR_RY1 + ns*7*512, 7, h1, lane);
      storeC16(Bb, SH, st*16, ns*16, h1, lane, true);
    }
    __syncthreads();
    { // y = hid @ ry2 + ryb2   K=64, N=128
      f32x4 y0 = cinit(ryb2, ns*32,      lane);
      f32x4 y1 = cinit(ryb2, ns*32 + 16, lane);
      y0 = mfma_tile(actB, SH, Wr + WR_RY2 + (ns*2+0)*2*512, 2, y0, lane);
      y1 = mfma_tile(actB, SH, Wr + WR_RY2 + (ns*2+1)*2*512, 2, y1, lane);
      storeC16(Az, SAZ, st*16, ns*32,      y0, lane, false);
      storeC16(Az, SAZ, st*16, ns*32 + 16, y1, lane, false);
    }
    __syncthreads();
  }

  // selector
  {
    f32x4 s1 = cinit(sb1, ns*16, lane);
    s1 = mfma_tile(actA, SAZ, SMW + OS1 + ns*4*512, 4, s1, lane);
    storeC16(Bb, SH, st*16, ns*16, s1, lane, true);
  }
  __syncthreads();
  {
    f32x4 lg = cinit(sb2, ns*16, lane);
    lg = mfma_tile(actB, SH, SMW + OS2 + ns*2*512, 2, lg, lane);
    int col = ns*16 + (lane & 15);
    int r0  = st*16 + (lane >> 4) * 4;
    #pragma unroll
    for (int rr = 0; rr < 4; ++rr)
      Lb[(r0+rr)*SLOG + col] = lg[rr] + gum[(size_t)(s0 + r0 + rr)*64 + col];
  }
  __syncthreads();

  // softmax (16 threads/sample, redundant row reduce)
  {
    const float* row = Lb + slane*SLOG;
    float m = -3.0e38f;
    #pragma unroll
    for (int k4 = 0; k4 < 16; ++k4){
      float4 v = *(const float4*)(row + k4*4);
      m = fmaxf(m, fmaxf(fmaxf(v.x,v.y), fmaxf(v.z,v.w)));
    }
    float ssum = 0.f;
    #pragma unroll
    for (int k4 = 0; k4 < 16; ++k4){
      float4 v = *(const float4*)(row + k4*4);
      ssum += __expf(v.x-m)+__expf(v.y-m)+__expf(v.z-m)+__expf(v.w-m);
    }
    float inv = 1.0f / ssum;
    const size_t gsamp = (size_t)(s0 + slane);
    #pragma unroll
    for (int j = 0; j < 4; ++j){
      int o = flane + 16*j;
      out[gsamp*64 + o] = __expf(row[o]-m) * inv;
    }
  }
}

extern "C" void kernel_launch(void* const* d_in, const int* in_sizes, int n_in,
                              void* d_out, int out_size, void* d_ws, size_t ws_size,
                              hipStream_t stream) {
  const int*   grd   = (const int*)d_in[0];
  const float* gfeat = (const float*)d_in[1];
  const float* gum   = (const float*)d_in[2];
  const float* w1    = (const float*)d_in[3];
  const float* b1    = (const float*)d_in[4];
  const float* w2    = (const float*)d_in[5];
  const float* b2    = (const float*)d_in[6];
  const float* wy    = (const float*)d_in[7];
  const float* byb   = (const float*)d_in[8];
  const float* wz    = (const float*)d_in[9];
  const float* bz    = (const float*)d_in[10];
  const float* rz1   = (const float*)d_in[11];
  const float* rzb1  = (const float*)d_in[12];
  const float* rz2   = (const float*)d_in[13];
  const float* rzb2  = (const float*)d_in[14];
  const float* ry1   = (const float*)d_in[15];
  const float* ryb1  = (const float*)d_in[16];
  const float* ry2   = (const float*)d_in[17];
  const float* ryb2  = (const float*)d_in[18];
  const float* sel1  = (const float*)d_in[19];
  const float* sb1   = (const float*)d_in[20];
  const float* sel2  = (const float*)d_in[21];
  const float* sb2   = (const float*)d_in[22];

  f16* ws = (f16*)d_ws;
  float* outp = (float*)d_out;

  const int prep_total = 9000*128 + 11264 + N_SMH;   // 1,257,472 = 4912*256
  prep_kernel<<<prep_total/256, 256, 0, stream>>>(
      w1, w2, wy, wz, rz1, rz2, ry1, ry2, sel1, sel2, ws);

  fused_kernel<<<8192/BM, WG_SIZE, 0, stream>>>(
      grd, gfeat, gum, b1, b2, byb, bz, rzb1, rzb2, ryb1, ryb2, sb1, sb2, ws, outp);
}